// Round 2
// baseline (411.682 us; speedup 1.0000x reference)
//
#include <hip/hip_runtime.h>

#define S    4096
#define DM   1024
#define H    16
#define DK   64

typedef __bf16 bf16;
typedef __bf16 bf16x8 __attribute__((ext_vector_type(8)));
typedef __bf16 bf16x4 __attribute__((ext_vector_type(4)));
typedef float  f32x4  __attribute__((ext_vector_type(4)));

// ---------------------------------------------------------------------------
// fp32 -> bf16 bulk convert: x (4M elems) + Wq/Wk/Wv/Wo (1M each) = 8M elems.
// ---------------------------------------------------------------------------
__global__ __launch_bounds__(256)
void convert_kernel(const float* __restrict__ x,  const float* __restrict__ wq,
                    const float* __restrict__ wk, const float* __restrict__ wv,
                    const float* __restrict__ wo,
                    bf16* __restrict__ xb,  bf16* __restrict__ wqb,
                    bf16* __restrict__ wkb, bf16* __restrict__ wvb,
                    bf16* __restrict__ wob)
{
    const size_t i = (size_t)blockIdx.x * 256 + threadIdx.x;   // f32x4 index
    const float* src; bf16* dst; size_t off;
    if (i < 1048576)      { src = x;  dst = xb;  off = i; }
    else if (i < 1310720) { src = wq; dst = wqb; off = i - 1048576; }
    else if (i < 1572864) { src = wk; dst = wkb; off = i - 1310720; }
    else if (i < 1835008) { src = wv; dst = wvb; off = i - 1572864; }
    else                  { src = wo; dst = wob; off = i - 1835008; }
    f32x4 v = ((const f32x4*)src)[off];
    bf16x4 b;
    for (int r = 0; r < 4; r++) b[r] = (bf16)v[r];
    ((bf16x4*)dst)[off] = b;
}

// ---------------------------------------------------------------------------
// GEMM: C(4096xDM) = A @ W^T, bf16 in, fp32 MFMA acc. 64x64 tile, 4 waves
// 2x2, BK=64 (R11: halves barrier count vs R8's BK=32; LDS stride 72 keeps
// bank aliasing <= 2-way = free). DO NOT enlarge to 128^2 tile: measured
// 2x-regressed twice (64B-sector write amplification + 3 blocks/CU).
// mode = base_mode + blockIdx.z:
//   0: Q  -> fused RoPE, *0.125*log2(e) (exp2 fold), bf16 [h][s][d]
//   1: K  -> fused RoPE,                             bf16 [h][s][d]
//   2: V  ->                bf16 [h][d][s] (transposed)
//   3: out ->               fp32 [m][n] to d_out
// ---------------------------------------------------------------------------
__global__ __launch_bounds__(256)
void gemm_kernel(const bf16* __restrict__ A,
                 const bf16* __restrict__ w0, const bf16* __restrict__ w1,
                 const bf16* __restrict__ w2,
                 const int* __restrict__ pos,
                 bf16* __restrict__ o0, bf16* __restrict__ o1,
                 bf16* __restrict__ o2,
                 float* __restrict__ of,
                 int base_mode)
{
    const int z    = blockIdx.z;
    const int mode = base_mode + z;
    const bf16* W  = (z == 0) ? w0 : (z == 1 ? w1 : w2);
    bf16* Out      = (z == 0) ? o0 : (z == 1 ? o1 : o2);

    __shared__ bf16 As[64 * 72];
    __shared__ bf16 Bs[64 * 72];

    const int tid  = threadIdx.x;
    const int lane = tid & 63;
    const int wv   = tid >> 6;
    const int quad = lane >> 4;
    const int col  = lane & 15;
    const int wm   = wv >> 1, wn = wv & 1;

    const int tileM = blockIdx.x * 64;
    const int tileN = blockIdx.y * 64;

    const int ldRow = tid >> 2;         // 0..63
    const int ldK   = (tid & 3) * 16;   // 0,16,32,48 (elements)

    f32x4 acc[2][2] = {};

    for (int kc = 0; kc < DM; kc += 64) {
        bf16x8 a0 = *(const bf16x8*)&A[(size_t)(tileM + ldRow) * DM + kc + ldK];
        bf16x8 a1 = *(const bf16x8*)&A[(size_t)(tileM + ldRow) * DM + kc + ldK + 8];
        bf16x8 b0 = *(const bf16x8*)&W[(size_t)(tileN + ldRow) * DM + kc + ldK];
        bf16x8 b1 = *(const bf16x8*)&W[(size_t)(tileN + ldRow) * DM + kc + ldK + 8];
        __syncthreads();                       // prior-iter LDS reads done
        *(bf16x8*)&As[ldRow * 72 + ldK]     = a0;
        *(bf16x8*)&As[ldRow * 72 + ldK + 8] = a1;
        *(bf16x8*)&Bs[ldRow * 72 + ldK]     = b0;
        *(bf16x8*)&Bs[ldRow * 72 + ldK + 8] = b1;
        __syncthreads();

        for (int kk = 0; kk < 2; kk++) {
            bf16x8 af0 = *(const bf16x8*)&As[(wm * 32 + 0 * 16 + col) * 72 + kk * 32 + quad * 8];
            bf16x8 af1 = *(const bf16x8*)&As[(wm * 32 + 1 * 16 + col) * 72 + kk * 32 + quad * 8];
            bf16x8 bf0 = *(const bf16x8*)&Bs[(wn * 32 + 0 * 16 + col) * 72 + kk * 32 + quad * 8];
            bf16x8 bf1 = *(const bf16x8*)&Bs[(wn * 32 + 1 * 16 + col) * 72 + kk * 32 + quad * 8];

            acc[0][0] = __builtin_amdgcn_mfma_f32_16x16x32_bf16(af0, bf0, acc[0][0], 0, 0, 0);
            acc[0][1] = __builtin_amdgcn_mfma_f32_16x16x32_bf16(af0, bf1, acc[0][1], 0, 0, 0);
            acc[1][0] = __builtin_amdgcn_mfma_f32_16x16x32_bf16(af1, bf0, acc[1][0], 0, 0, 0);
            acc[1][1] = __builtin_amdgcn_mfma_f32_16x16x32_bf16(af1, bf1, acc[1][1], 0, 0, 0);
        }
    }

    // Epilogue. C/D layout: col = lane&15, row = quad*4 + r  [m89/m91]
    for (int fm = 0; fm < 2; fm++)
    for (int fn = 0; fn < 2; fn++) {
        f32x4 v = acc[fm][fn];
        const int n = tileN + wn * 32 + fn * 16 + col;
        for (int r = 0; r < 4; r++) {
            const int m = tileM + wm * 32 + fm * 16 + quad * 4 + r;
            float val = v[r];
            if (mode <= 1) {
                // RoPE: pairs (2i,2i+1); partner value lives in lane^1
                float part = __shfl_xor(val, 1);
                const int d = n & 63;
                const int i = d >> 1;
                float inv = exp2f(-(float)i * 0.41524101186092034f); // 1e4^(-i/32)
                float ang = (float)pos[m] * inv;
                float c = cosf(ang), sn = sinf(ang);
                float rot = (n & 1) ? (val * c + part * sn)
                                    : (val * c - part * sn);
                // Q: fold 1/sqrt(DK) AND log2(e) so attn can use raw exp2
                if (mode == 0) rot *= 0.18033688011112042f;   // 0.125*log2(e)
                Out[((size_t)(n >> 6) * S + m) * 64 + d] = (bf16)rot;
            } else if (mode == 2) {
                Out[(size_t)n * S + m] = (bf16)val;           // V^T [h][d][s]
            } else {
                of[(size_t)m * DM + n] = val;                 // d_out fp32
            }
        }
    }
}

// ---------------------------------------------------------------------------
// Flash attention (causal), transposed scores: St = K.Q^T, col = query.
// UNSHIFTED softmax -> partial (o,l) over disjoint key ranges sum linearly.
// R13: NO K/V LDS STAGING. R1 counters: 96 KB/block-tile LDS traffic (4-wave
// duplicated fragment reads) = 65 us LDS-pipe floor per CU — the real limit.
// K/V fragments now read DIRECT from global (64B sectors): block-level dup
// absorbed by L1; K+V working set 2 MB/2 heads fits per-XCD L2 via the
// head-pinned swizzle below. No __syncthreads at all (waves independent);
// LDS = per-wave P buffer only (9 KB -> never the residency limit).
// Dispatch: bid&7 -> XCD owns heads {2x,2x+1}; qb descends 63..0 = LPT
// (longest blocks first -> no straggler tail, R1's split-K failure mode).
// ---------------------------------------------------------------------------
__global__ __launch_bounds__(256, 4)
void attn_kernel(const bf16* __restrict__ q, const bf16* __restrict__ k,
                 const bf16* __restrict__ vt,
                 bf16* __restrict__ P0g, bf16* __restrict__ P1g,
                 float* __restrict__ l0g, float* __restrict__ l1g)
{
    const int bid  = blockIdx.x;
    const int xcd  = bid & 7;
    const int seq  = bid >> 3;            // 0..255
    const int h    = (xcd << 1) | (seq & 1);
    const int rest = seq >> 1;            // 0..127
    const int z    = rest & 1;
    const int qb_  = 63 - (rest >> 1);    // descending: longest first

    const int tid  = threadIdx.x;
    const int lane = tid & 63;
    const int wv   = tid >> 6;
    const int quad = lane >> 4;
    const int col  = lane & 15;

    const int nt   = qb_ + 1;             // total key tiles for this q block
    const int half = (nt + 1) >> 1;
    const int kt0  = z ? half : 0;
    const int kt1  = z ? nt   : half;

    __shared__ bf16 plds[4][16 * 72];     // per-wave P tile [q][key], padded

    const int qbase = qb_ * 64 + wv * 16;

    // Q as B-operand fragments: B[n=q=col][kdim=d]
    bf16x8 qf0 = *(const bf16x8*)&q[((size_t)(h * S + qbase + col)) * 64 + quad * 8];
    bf16x8 qf1 = *(const bf16x8*)&q[((size_t)(h * S + qbase + col)) * 64 + 32 + quad * 8];

    float li = 0.f;
    f32x4 o[4] = {};
    const int gq = qbase + col;

    // Per-lane global fragment pointers (advance by one tile per iter).
    // K row = key (kg*16+col), 8 k-elems at quad*8 (+32): 16 rows x 64B.
    // V row = d   (dg*16+col), 8 keys  at quad*8 (+32).
    const bf16* kp = k  + ((size_t)h * S + (size_t)kt0 * 64 + col) * 64 + quad * 8;
    const bf16* vp = vt + ((size_t)(h * 64 + col)) * S + (size_t)kt0 * 64 + quad * 8;

    for (int kt = kt0; kt < kt1; kt++) {
        const int kbase = kt * 64;

        // --- QK^T: A = K direct from global (L1/L2-served) ---
        bf16x8 kf[4][2];
#pragma unroll
        for (int kg = 0; kg < 4; kg++) {
            kf[kg][0] = *(const bf16x8*)(kp + kg * 16 * 64);
            kf[kg][1] = *(const bf16x8*)(kp + kg * 16 * 64 + 32);
        }
        f32x4 st[4];
        __builtin_amdgcn_s_setprio(1);
#pragma unroll
        for (int kg = 0; kg < 4; kg++) {
            f32x4 zz = {};
            zz = __builtin_amdgcn_mfma_f32_16x16x32_bf16(kf[kg][0], qf0, zz, 0, 0, 0);
            zz = __builtin_amdgcn_mfma_f32_16x16x32_bf16(kf[kg][1], qf1, zz, 0, 0, 0);
            st[kg] = zz;
        }
        __builtin_amdgcn_s_setprio(0);

        // --- V fragments issued now; latency hides under softmax below ---
        bf16x8 vf[4][2];
#pragma unroll
        for (int dg = 0; dg < 4; dg++) {
            vf[dg][0] = *(const bf16x8*)(vp + (size_t)dg * 16 * S);
            vf[dg][1] = *(const bf16x8*)(vp + (size_t)dg * 16 * S + 32);
        }
        kp += 64 * 64;
        vp += 64;

        // causal mask only on the diagonal tile (block-uniform branch)
        if (kt == qb_) {
#pragma unroll
            for (int kg = 0; kg < 4; kg++)
#pragma unroll
                for (int r = 0; r < 4; r++) {
                    const int gk = kbase + kg * 16 + quad * 4 + r;
                    st[kg][r] = (gk > gq) ? -1e30f : st[kg][r];
                }
        }

        // p = exp2(s) via raw v_exp_f32 (scores pre-scaled by log2e; bounded;
        // -1e30 mask -> 0). Saves the libm range-fixup VALU ops.
        float ps = 0.f;
#pragma unroll
        for (int kg = 0; kg < 4; kg++) {
            bf16x4 pk;
#pragma unroll
            for (int r = 0; r < 4; r++) {
                float p;
                asm("v_exp_f32 %0, %1" : "=v"(p) : "v"(st[kg][r]));
                ps += p;
                pk[r] = (bf16)p;
            }
            *(bf16x4*)&plds[wv][col * 72 + kg * 16 + quad * 4] = pk;  // packed b64
        }
        ps += __shfl_xor(ps, 16);
        ps += __shfl_xor(ps, 32);
        li += ps;

        __builtin_amdgcn_wave_barrier();   // keep P writes before P reads

        bf16x8 pb0 = *(const bf16x8*)&plds[wv][col * 72 + quad * 8];
        bf16x8 pb1 = *(const bf16x8*)&plds[wv][col * 72 + 32 + quad * 8];

        // O^T[d][q] += V^T[d][key] * P^T[key][q]
        __builtin_amdgcn_s_setprio(1);
#pragma unroll
        for (int dg = 0; dg < 4; dg++) {
            o[dg] = __builtin_amdgcn_mfma_f32_16x16x32_bf16(vf[dg][0], pb0, o[dg], 0, 0, 0);
            o[dg] = __builtin_amdgcn_mfma_f32_16x16x32_bf16(vf[dg][1], pb1, o[dg], 0, 0, 0);
        }
        __builtin_amdgcn_s_setprio(0);
    }

    // Epilogue: store UNNORMALIZED partial o (bf16) + partial l (fp32).
    // Empty ranges (z=1, qb_=0) store zeros -> combine stays branch-free.
    bf16*  Pz = z ? P1g : P0g;
    float* lz = z ? l1g : l0g;
#pragma unroll
    for (int dg = 0; dg < 4; dg++) {
        bf16x4 ov;
#pragma unroll
        for (int r = 0; r < 4; r++) ov[r] = (bf16)o[dg][r];
        // O^T: row = d = dg*16+quad*4+r, col = q -> P[s][h*64+d]
        *(bf16x4*)&Pz[(size_t)gq * DM + h * 64 + dg * 16 + quad * 4] = ov;
    }
    if (quad == 0) lz[(size_t)h * S + gq] = li;
}

// ---------------------------------------------------------------------------
// Combine split-K partials: ao[s][dm] = (P0 + P1) / (l0[h][s] + l1[h][s]).
// 24 MB traffic, mostly L2/L3-warm.
// ---------------------------------------------------------------------------
__global__ __launch_bounds__(256)
void combine_kernel(const bf16* __restrict__ P0, const bf16* __restrict__ P1,
                    const float* __restrict__ l0, const float* __restrict__ l1,
                    bf16* __restrict__ ao)
{
    const size_t i    = (size_t)blockIdx.x * 256 + threadIdx.x;  // 8-elem group
    const size_t base = i * 8;
    const int s  = (int)(base >> 10);          // DM = 1024
    const int dm = (int)(base & 1023);
    const int h  = dm >> 6;
    const float rli = 1.f / (l0[(size_t)h * S + s] + l1[(size_t)h * S + s]);
    bf16x8 a = *(const bf16x8*)&P0[base];
    bf16x8 b = *(const bf16x8*)&P1[base];
    bf16x8 ov;
    for (int r = 0; r < 8; r++)
        ov[r] = (bf16)(((float)a[r] + (float)b[r]) * rli);
    *(bf16x8*)&ao[base] = ov;
}

// ---------------------------------------------------------------------------
extern "C" void kernel_launch(void* const* d_in, const int* in_sizes, int n_in,
                              void* d_out, int out_size, void* d_ws, size_t ws_size,
                              hipStream_t stream)
{
    const float* x   = (const float*)d_in[0];
    const int*   pos = (const int*)d_in[1];
    const float* Wq  = (const float*)d_in[2];
    const float* Wk  = (const float*)d_in[3];
    const float* Wv  = (const float*)d_in[4];
    const float* Wo  = (const float*)d_in[5];
    float* out = (float*)d_out;   // reference output dtype is float32

    // workspace layout (48 MB), regions recycled across phases:
    //   [0, 8M)    xb  bf16 [s][DM]        -> P0 bf16 partial (after QKV gemm)
    //   [8,16M)    wqb/wkb/wvb             -> P1 bf16 partial (after QKV gemm)
    //   [16,24M)   qb  bf16 [h][s][d]      -> ao bf16 [s][DM] (after attn)
    //   [24,32M)   kb  bf16 [h][s][d]
    //   [32,40M)   vt  bf16 [h][d][s]
    //   [40,40.25M) l0 fp32 [h][s]   [40.25,40.5M) l1 fp32 [h][s]
    //   [46,48M)   wob bf16
    char* w = (char*)d_ws;
    bf16*  xb  = (bf16*)(w);
    bf16*  wqb = (bf16*)(w + (size_t) 8 * 1024 * 1024);
    bf16*  wkb = (bf16*)(w + (size_t)10 * 1024 * 1024);
    bf16*  wvb = (bf16*)(w + (size_t)12 * 1024 * 1024);
    bf16*  P0  = (bf16*)(w);
    bf16*  P1  = (bf16*)(w + (size_t) 8 * 1024 * 1024);
    bf16*  qb  = (bf16*)(w + (size_t)16 * 1024 * 1024);
    bf16*  kb  = (bf16*)(w + (size_t)24 * 1024 * 1024);
    bf16*  vt  = (bf16*)(w + (size_t)32 * 1024 * 1024);
    float* l0  = (float*)(w + (size_t)40 * 1024 * 1024);
    float* l1  = (float*)(w + (size_t)40 * 1024 * 1024 + 256 * 1024);
    bf16*  ao  = (bf16*)(w + (size_t)16 * 1024 * 1024);   // alias qb (dead)
    bf16*  wob = (bf16*)(w + (size_t)46 * 1024 * 1024);

    dim3 blk(256);
    convert_kernel<<<dim3(8192), blk, 0, stream>>>(x, Wq, Wk, Wv, Wo,
                                                   xb, wqb, wkb, wvb, wob);
    gemm_kernel<<<dim3(64, 16, 3), blk, 0, stream>>>(xb, wqb, wkb, wvb, pos,
                                                     qb, kb, vt, out, 0);
    attn_kernel<<<dim3(2048), blk, 0, stream>>>(qb, kb, vt,
                                                P0, P1, l0, l1);
    combine_kernel<<<dim3(2048), blk, 0, stream>>>(P0, P1, l0, l1, ao);
    gemm_kernel<<<dim3(64, 16, 1), blk, 0, stream>>>(ao, wob, wob, wob, pos,
                                                     P0, P0, P0, out, 3);
}

// Round 3
// 230.034 us; speedup vs baseline: 1.7897x; 1.7897x over previous
//
#include <hip/hip_runtime.h>

#define S    4096
#define DM   1024
#define H    16
#define DK   64

typedef __bf16 bf16;
typedef __bf16 bf16x8 __attribute__((ext_vector_type(8)));
typedef __bf16 bf16x4 __attribute__((ext_vector_type(4)));
typedef float  f32x4  __attribute__((ext_vector_type(4)));

// ---------------------------------------------------------------------------
// fp32 -> bf16 bulk convert: x (4M elems) + Wq/Wk/Wv/Wo (1M each) = 8M elems.
// ---------------------------------------------------------------------------
__global__ __launch_bounds__(256)
void convert_kernel(const float* __restrict__ x,  const float* __restrict__ wq,
                    const float* __restrict__ wk, const float* __restrict__ wv,
                    const float* __restrict__ wo,
                    bf16* __restrict__ xb,  bf16* __restrict__ wqb,
                    bf16* __restrict__ wkb, bf16* __restrict__ wvb,
                    bf16* __restrict__ wob)
{
    const size_t i = (size_t)blockIdx.x * 256 + threadIdx.x;   // f32x4 index
    const float* src; bf16* dst; size_t off;
    if (i < 1048576)      { src = x;  dst = xb;  off = i; }
    else if (i < 1310720) { src = wq; dst = wqb; off = i - 1048576; }
    else if (i < 1572864) { src = wk; dst = wkb; off = i - 1310720; }
    else if (i < 1835008) { src = wv; dst = wvb; off = i - 1572864; }
    else                  { src = wo; dst = wob; off = i - 1835008; }
    f32x4 v = ((const f32x4*)src)[off];
    bf16x4 b;
    for (int r = 0; r < 4; r++) b[r] = (bf16)v[r];
    ((bf16x4*)dst)[off] = b;
}

// ---------------------------------------------------------------------------
// GEMM: C(4096xDM) = A @ W^T, bf16 in, fp32 MFMA acc. 64x64 tile, 4 waves
// 2x2, BK=64. DO NOT enlarge to 128^2 tile: measured 2x-regressed twice.
// mode = base_mode + blockIdx.z:
//   0: Q  -> fused RoPE, *0.125*log2(e) (exp2 fold), bf16 [h][s][d]
//   1: K  -> fused RoPE,                             bf16 [h][s][d]
//   2: V  ->                bf16 [h][d][s] (transposed)
//   3: out ->               fp32 [m][n] to d_out
// ---------------------------------------------------------------------------
__global__ __launch_bounds__(256)
void gemm_kernel(const bf16* __restrict__ A,
                 const bf16* __restrict__ w0, const bf16* __restrict__ w1,
                 const bf16* __restrict__ w2,
                 const int* __restrict__ pos,
                 bf16* __restrict__ o0, bf16* __restrict__ o1,
                 bf16* __restrict__ o2,
                 float* __restrict__ of,
                 int base_mode)
{
    const int z    = blockIdx.z;
    const int mode = base_mode + z;
    const bf16* W  = (z == 0) ? w0 : (z == 1 ? w1 : w2);
    bf16* Out      = (z == 0) ? o0 : (z == 1 ? o1 : o2);

    __shared__ bf16 As[64 * 72];
    __shared__ bf16 Bs[64 * 72];

    const int tid  = threadIdx.x;
    const int lane = tid & 63;
    const int wv   = tid >> 6;
    const int quad = lane >> 4;
    const int col  = lane & 15;
    const int wm   = wv >> 1, wn = wv & 1;

    const int tileM = blockIdx.x * 64;
    const int tileN = blockIdx.y * 64;

    const int ldRow = tid >> 2;         // 0..63
    const int ldK   = (tid & 3) * 16;   // 0,16,32,48 (elements)

    f32x4 acc[2][2] = {};

    for (int kc = 0; kc < DM; kc += 64) {
        bf16x8 a0 = *(const bf16x8*)&A[(size_t)(tileM + ldRow) * DM + kc + ldK];
        bf16x8 a1 = *(const bf16x8*)&A[(size_t)(tileM + ldRow) * DM + kc + ldK + 8];
        bf16x8 b0 = *(const bf16x8*)&W[(size_t)(tileN + ldRow) * DM + kc + ldK];
        bf16x8 b1 = *(const bf16x8*)&W[(size_t)(tileN + ldRow) * DM + kc + ldK + 8];
        __syncthreads();                       // prior-iter LDS reads done
        *(bf16x8*)&As[ldRow * 72 + ldK]     = a0;
        *(bf16x8*)&As[ldRow * 72 + ldK + 8] = a1;
        *(bf16x8*)&Bs[ldRow * 72 + ldK]     = b0;
        *(bf16x8*)&Bs[ldRow * 72 + ldK + 8] = b1;
        __syncthreads();

        for (int kk = 0; kk < 2; kk++) {
            bf16x8 af0 = *(const bf16x8*)&As[(wm * 32 + 0 * 16 + col) * 72 + kk * 32 + quad * 8];
            bf16x8 af1 = *(const bf16x8*)&As[(wm * 32 + 1 * 16 + col) * 72 + kk * 32 + quad * 8];
            bf16x8 bf0 = *(const bf16x8*)&Bs[(wn * 32 + 0 * 16 + col) * 72 + kk * 32 + quad * 8];
            bf16x8 bf1 = *(const bf16x8*)&Bs[(wn * 32 + 1 * 16 + col) * 72 + kk * 32 + quad * 8];

            acc[0][0] = __builtin_amdgcn_mfma_f32_16x16x32_bf16(af0, bf0, acc[0][0], 0, 0, 0);
            acc[0][1] = __builtin_amdgcn_mfma_f32_16x16x32_bf16(af0, bf1, acc[0][1], 0, 0, 0);
            acc[1][0] = __builtin_amdgcn_mfma_f32_16x16x32_bf16(af1, bf0, acc[1][0], 0, 0, 0);
            acc[1][1] = __builtin_amdgcn_mfma_f32_16x16x32_bf16(af1, bf1, acc[1][1], 0, 0, 0);
        }
    }

    // Epilogue. C/D layout: col = lane&15, row = quad*4 + r  [m89/m91]
    for (int fm = 0; fm < 2; fm++)
    for (int fn = 0; fn < 2; fn++) {
        f32x4 v = acc[fm][fn];
        const int n = tileN + wn * 32 + fn * 16 + col;
        for (int r = 0; r < 4; r++) {
            const int m = tileM + wm * 32 + fm * 16 + quad * 4 + r;
            float val = v[r];
            if (mode <= 1) {
                // RoPE: pairs (2i,2i+1); partner value lives in lane^1
                float part = __shfl_xor(val, 1);
                const int d = n & 63;
                const int i = d >> 1;
                float inv = exp2f(-(float)i * 0.41524101186092034f); // 1e4^(-i/32)
                float ang = (float)pos[m] * inv;
                float c = cosf(ang), sn = sinf(ang);
                float rot = (n & 1) ? (val * c + part * sn)
                                    : (val * c - part * sn);
                // Q: fold 1/sqrt(DK) AND log2(e) so attn can use raw exp2
                if (mode == 0) rot *= 0.18033688011112042f;   // 0.125*log2(e)
                Out[((size_t)(n >> 6) * S + m) * 64 + d] = (bf16)rot;
            } else if (mode == 2) {
                Out[(size_t)n * S + m] = (bf16)val;           // V^T [h][d][s]
            } else {
                of[(size_t)m * DM + n] = val;                 // d_out fp32
            }
        }
    }
}

// ---------------------------------------------------------------------------
// Flash attention (causal), transposed scores: St = K.Q^T, col = query.
// UNSHIFTED softmax -> partial (o,l) over disjoint key ranges sum linearly.
// R3: 64 QUERIES PER WAVE (block = 4 waves x 64 q = 256 q). R1's floor was
// LDS-pipe: 4 waves re-read the full K/V tile for only 16 q each. Now the
// same 16 K/V b128 reads/wave feed 4x the MFMA work -> LDS floor ~31us/CU.
// P goes through LDS in 32-key halves (plds [64 q][40] per wave, 5KB).
// Grid: 512 blocks = 16 QB x 16 h x 2 split-K halves = exactly 2/CU, all
// resident. Antithetic mapping: QB = (b3==b8)? 15-u : u, z=b3, h-bit=b8 ->
// any CU-mate pair (flip bit3 [depth-first fill] or bit8 [breadth-first])
// sums to exactly 34 tiles -> near-perfect balance either way.
// XCD head-pinning kept (R2 verified: FETCH 51->12 GB).
// ---------------------------------------------------------------------------
__global__ __launch_bounds__(256, 2)
void attn_kernel(const bf16* __restrict__ q, const bf16* __restrict__ k,
                 const bf16* __restrict__ vt,
                 bf16* __restrict__ P0g, bf16* __restrict__ P1g,
                 float* __restrict__ l0g, float* __restrict__ l1g)
{
    const int bid = blockIdx.x;
    const int xcd = bid & 7;
    const int b3  = (bid >> 3) & 1;
    const int u   = (bid >> 4) & 15;
    const int b8  = (bid >> 8) & 1;
    const int h   = (xcd << 1) | b8;
    const int z   = b3;
    const int QB  = (b3 == b8) ? (15 - u) : u;   // antithetic pair balance

    const int tid  = threadIdx.x;
    const int lane = tid & 63;
    const int wv   = tid >> 6;
    const int quad = lane >> 4;
    const int col  = lane & 15;

    const int T2  = 2 * QB + 2;          // tiles per split-K chunk
    const int kt0 = z * T2;
    const int kt1 = kt0 + T2;

    __shared__ bf16 Ks[64 * 72];         // K[key][d],   padded (2-way free)
    __shared__ bf16 Vs[64 * 72];         // V^T[d][key], padded
    __shared__ bf16 plds[4][64 * 40];    // per-wave P half-tile [q][32key+pad]

    const int qbase = QB * 256 + wv * 64;    // wave owns 64 queries

    // Q as B-operand fragments: B[n=q][kdim=d], 4 q-groups of 16
    bf16x8 qf[4][2];
#pragma unroll
    for (int qt = 0; qt < 4; qt++) {
        const bf16* qr = &q[((size_t)(h * S + qbase + qt * 16 + col)) * 64];
        qf[qt][0] = *(const bf16x8*)(qr + quad * 8);
        qf[qt][1] = *(const bf16x8*)(qr + 32 + quad * 8);
    }

    float li[4] = {};
    f32x4 o[4][4] = {};                  // [dg][qt]

    const int srow = tid >> 2;
    const int sseg = (tid & 3) * 16;
    const bf16* kg_ = k  + ((size_t)h * S) * 64;
    const bf16* vg_ = vt + ((size_t)h * 64) * S;

    // preload first tile of this chunk
    bf16x8 kr0 = *(const bf16x8*)(kg_ + (size_t)(kt0 * 64 + srow) * 64 + sseg);
    bf16x8 kr1 = *(const bf16x8*)(kg_ + (size_t)(kt0 * 64 + srow) * 64 + sseg + 8);
    bf16x8 vr0 = *(const bf16x8*)(vg_ + (size_t)srow * S + kt0 * 64 + sseg);
    bf16x8 vr1 = *(const bf16x8*)(vg_ + (size_t)srow * S + kt0 * 64 + sseg + 8);

    for (int kt = kt0; kt < kt1; kt++) {
        const int kbase = kt * 64;

        __syncthreads();                 // prior-iter LDS fragment reads done
        *(bf16x8*)&Ks[srow * 72 + sseg]     = kr0;
        *(bf16x8*)&Ks[srow * 72 + sseg + 8] = kr1;
        *(bf16x8*)&Vs[srow * 72 + sseg]     = vr0;
        *(bf16x8*)&Vs[srow * 72 + sseg + 8] = vr1;
        __syncthreads();

        // register-prefetch next tile (overlaps with compute below)
        if (kt + 1 < kt1) {
            const int nb = kbase + 64;
            kr0 = *(const bf16x8*)(kg_ + (size_t)(nb + srow) * 64 + sseg);
            kr1 = *(const bf16x8*)(kg_ + (size_t)(nb + srow) * 64 + sseg + 8);
            vr0 = *(const bf16x8*)(vg_ + (size_t)srow * S + nb + sseg);
            vr1 = *(const bf16x8*)(vg_ + (size_t)srow * S + nb + sseg + 8);
        }

        const bool diag = (kt >= (QB << 2));   // tile overlaps causal diagonal

        // Process 64 keys in two 32-key halves (plds holds one half)
#pragma unroll
        for (int half = 0; half < 2; half++) {
            __builtin_amdgcn_wave_barrier();   // prior half's P reads done
#pragma unroll
            for (int kg2 = 0; kg2 < 2; kg2++) {
                const int kg = half * 2 + kg2;
                // K A-fragments (shared across the 4 q-groups)
                bf16x8 kf0 = *(const bf16x8*)&Ks[(kg * 16 + col) * 72 + quad * 8];
                bf16x8 kf1 = *(const bf16x8*)&Ks[(kg * 16 + col) * 72 + 32 + quad * 8];

                f32x4 st[4];
                __builtin_amdgcn_s_setprio(1);
#pragma unroll
                for (int qt = 0; qt < 4; qt++) {
                    f32x4 zz = {};
                    zz = __builtin_amdgcn_mfma_f32_16x16x32_bf16(kf0, qf[qt][0], zz, 0, 0, 0);
                    zz = __builtin_amdgcn_mfma_f32_16x16x32_bf16(kf1, qf[qt][1], zz, 0, 0, 0);
                    st[qt] = zz;
                }
                __builtin_amdgcn_s_setprio(0);

                if (diag) {
#pragma unroll
                    for (int qt = 0; qt < 4; qt++) {
                        const int gq = qbase + qt * 16 + col;
#pragma unroll
                        for (int r = 0; r < 4; r++) {
                            const int gk = kbase + kg * 16 + quad * 4 + r;
                            st[qt][r] = (gk > gq) ? -1e30f : st[qt][r];
                        }
                    }
                }

                // p = exp2(s) raw; accumulate per-lane partial l (reduce once
                // at the end); write P half-tile (b64, packed)
#pragma unroll
                for (int qt = 0; qt < 4; qt++) {
                    bf16x4 pk;
#pragma unroll
                    for (int r = 0; r < 4; r++) {
                        float p;
                        asm("v_exp_f32 %0, %1" : "=v"(p) : "v"(st[qt][r]));
                        li[qt] += p;
                        pk[r] = (bf16)p;
                    }
                    *(bf16x4*)&plds[wv][(qt * 16 + col) * 40 + kg2 * 16 + quad * 4] = pk;
                }
            }

            __builtin_amdgcn_wave_barrier();   // P writes before P reads

            // PV for this 32-key half: O^T[d][q] += V^T[d][key] * P^T[key][q]
            bf16x8 pb[4];
#pragma unroll
            for (int qt = 0; qt < 4; qt++)
                pb[qt] = *(const bf16x8*)&plds[wv][(qt * 16 + col) * 40 + quad * 8];

            __builtin_amdgcn_s_setprio(1);
#pragma unroll
            for (int dg = 0; dg < 4; dg++) {
                bf16x8 va = *(const bf16x8*)&Vs[(dg * 16 + col) * 72 + half * 32 + quad * 8];
#pragma unroll
                for (int qt = 0; qt < 4; qt++)
                    o[dg][qt] = __builtin_amdgcn_mfma_f32_16x16x32_bf16(va, pb[qt], o[dg][qt], 0, 0, 0);
            }
            __builtin_amdgcn_s_setprio(0);
        }
    }

    // Cross-quad l reduction (keys split across quads), once per kernel
#pragma unroll
    for (int qt = 0; qt < 4; qt++) {
        li[qt] += __shfl_xor(li[qt], 16);
        li[qt] += __shfl_xor(li[qt], 32);
    }

    // Epilogue: store UNNORMALIZED partial o (bf16) + partial l (fp32).
    bf16*  Pz = z ? P1g : P0g;
    float* lz = z ? l1g : l0g;
#pragma unroll
    for (int dg = 0; dg < 4; dg++)
#pragma unroll
    for (int qt = 0; qt < 4; qt++) {
        const int gq = qbase + qt * 16 + col;
        bf16x4 ov;
#pragma unroll
        for (int r = 0; r < 4; r++) ov[r] = (bf16)o[dg][qt][r];
        *(bf16x4*)&Pz[(size_t)gq * DM + h * 64 + dg * 16 + quad * 4] = ov;
    }
    if (quad == 0) {
#pragma unroll
        for (int qt = 0; qt < 4; qt++)
            lz[(size_t)h * S + qbase + qt * 16 + col] = li[qt];
    }
}

// ---------------------------------------------------------------------------
// Combine split-K partials: ao[s][dm] = (P0 + P1) / (l0[h][s] + l1[h][s]).
// ---------------------------------------------------------------------------
__global__ __launch_bounds__(256)
void combine_kernel(const bf16* __restrict__ P0, const bf16* __restrict__ P1,
                    const float* __restrict__ l0, const float* __restrict__ l1,
                    bf16* __restrict__ ao)
{
    const size_t i    = (size_t)blockIdx.x * 256 + threadIdx.x;  // 8-elem group
    const size_t base = i * 8;
    const int s  = (int)(base >> 10);          // DM = 1024
    const int dm = (int)(base & 1023);
    const int h  = dm >> 6;
    const float rli = 1.f / (l0[(size_t)h * S + s] + l1[(size_t)h * S + s]);
    bf16x8 a = *(const bf16x8*)&P0[base];
    bf16x8 b = *(const bf16x8*)&P1[base];
    bf16x8 ov;
    for (int r = 0; r < 8; r++)
        ov[r] = (bf16)(((float)a[r] + (float)b[r]) * rli);
    *(bf16x8*)&ao[base] = ov;
}

// ---------------------------------------------------------------------------
extern "C" void kernel_launch(void* const* d_in, const int* in_sizes, int n_in,
                              void* d_out, int out_size, void* d_ws, size_t ws_size,
                              hipStream_t stream)
{
    const float* x   = (const float*)d_in[0];
    const int*   pos = (const int*)d_in[1];
    const float* Wq  = (const float*)d_in[2];
    const float* Wk  = (const float*)d_in[3];
    const float* Wv  = (const float*)d_in[4];
    const float* Wo  = (const float*)d_in[5];
    float* out = (float*)d_out;   // reference output dtype is float32

    // workspace layout (48 MB), regions recycled across phases:
    //   [0, 8M)    xb  bf16 [s][DM]        -> P0 bf16 partial (after QKV gemm)
    //   [8,16M)    wqb/wkb/wvb             -> P1 bf16 partial (after QKV gemm)
    //   [16,24M)   qb  bf16 [h][s][d]      -> ao bf16 [s][DM] (after attn)
    //   [24,32M)   kb  bf16 [h][s][d]
    //   [32,40M)   vt  bf16 [h][d][s]
    //   [40,40.25M) l0 fp32 [h][s]   [40.25,40.5M) l1 fp32 [h][s]
    //   [46,48M)   wob bf16
    char* w = (char*)d_ws;
    bf16*  xb  = (bf16*)(w);
    bf16*  wqb = (bf16*)(w + (size_t) 8 * 1024 * 1024);
    bf16*  wkb = (bf16*)(w + (size_t)10 * 1024 * 1024);
    bf16*  wvb = (bf16*)(w + (size_t)12 * 1024 * 1024);
    bf16*  P0  = (bf16*)(w);
    bf16*  P1  = (bf16*)(w + (size_t) 8 * 1024 * 1024);
    bf16*  qb  = (bf16*)(w + (size_t)16 * 1024 * 1024);
    bf16*  kb  = (bf16*)(w + (size_t)24 * 1024 * 1024);
    bf16*  vt  = (bf16*)(w + (size_t)32 * 1024 * 1024);
    float* l0  = (float*)(w + (size_t)40 * 1024 * 1024);
    float* l1  = (float*)(w + (size_t)40 * 1024 * 1024 + 256 * 1024);
    bf16*  ao  = (bf16*)(w + (size_t)16 * 1024 * 1024);   // alias qb (dead)
    bf16*  wob = (bf16*)(w + (size_t)46 * 1024 * 1024);

    dim3 blk(256);
    convert_kernel<<<dim3(8192), blk, 0, stream>>>(x, Wq, Wk, Wv, Wo,
                                                   xb, wqb, wkb, wvb, wob);
    gemm_kernel<<<dim3(64, 16, 3), blk, 0, stream>>>(xb, wqb, wkb, wvb, pos,
                                                     qb, kb, vt, out, 0);
    attn_kernel<<<dim3(512), blk, 0, stream>>>(qb, kb, vt,
                                               P0, P1, l0, l1);
    combine_kernel<<<dim3(2048), blk, 0, stream>>>(P0, P1, l0, l1, ao);
    gemm_kernel<<<dim3(64, 16, 1), blk, 0, stream>>>(ao, wob, wob, wob, pos,
                                                     P0, P0, P0, out, 3);
}